// Round 5
// baseline (1687.933 us; speedup 1.0000x reference)
//
#include <hip/hip_runtime.h>
#include <math.h>

#define NN 50000
#define NE 800000
#define TDIM 100

typedef _Float16 half2v __attribute__((ext_vector_type(2)));
typedef _Float16 half4v __attribute__((ext_vector_type(4)));
typedef _Float16 half8v __attribute__((ext_vector_type(8)));
typedef __fp16 fp16x2 __attribute__((ext_vector_type(2)));
typedef float f32x4 __attribute__((ext_vector_type(4)));

union U16 { uint4 u; half8v h; };
union U4h { unsigned u; half2v h; };

// cos(x) matching np.cos(float32) to ~1e-6: Cody-Waite into revolutions +
// hardware v_cos_f32.
__device__ __forceinline__ float ref_cosf(float x) {
  const float C1 = 0.15915494f;
  const float C2 = 6.42063831e-9f;
  float p = x * C1;
  float r = __fmaf_rn(x, C1, -p);
  r = __fmaf_rn(x, C2, r);
  float n = rintf(p);
  float f = (p - n) + r;
  return __builtin_amdgcn_cosf(f);
}

__device__ __forceinline__ float fdot2f(unsigned a, unsigned b, float c) {
  U4h ua, ub; ua.u = a; ub.u = b;
#if __has_builtin(__builtin_amdgcn_fdot2)
  return __builtin_amdgcn_fdot2(ua.h, ub.h, c, false);
#else
  return c + (float)ua.h.x * (float)ub.h.x + (float)ua.h.y * (float)ub.h.y;
#endif
}

__device__ __forceinline__ unsigned pk16(float a, float b) {
  fp16x2 h = __builtin_amdgcn_cvt_pkrtz(a, b);
  unsigned u;
  __builtin_memcpy(&u, &h, 4);
  return u;
}

// ---------------- projection GEMM + fused Z ----------------
// [NN,128] x [128,512] -> Q16|K16|V16|S16 (all f16).
// cy in {0,1} blocks additionally compute Z[n][h][j] = q_h . We_h[j]
// for their two heads (cy=0: h0,1; cy=1: h2,3) -> Z16 [n][4][104] f16.
#define PBK 16
__global__ void k_proj(
    const float* __restrict__ x,
    const float* __restrict__ Wq, const float* __restrict__ bq,
    const float* __restrict__ Wk, const float* __restrict__ bk,
    const float* __restrict__ Wv, const float* __restrict__ bv,
    const float* __restrict__ Wskip, const float* __restrict__ bskip,
    const float* __restrict__ We,
    _Float16* __restrict__ Q16, _Float16* __restrict__ K16,
    _Float16* __restrict__ V16, _Float16* __restrict__ S16,
    _Float16* __restrict__ Z16)
{
  __shared__ float a_s[PBK][68];
  __shared__ float b_s[PBK][64];
  __shared__ unsigned qs2[64][32];     // q as f16x2 pairs [row][k-pair]
  __shared__ unsigned wes2[8][104];    // We slice f16x2 [k-pair][j]

  const int tid = threadIdx.x;
  const int cy = blockIdx.x;              // 0..7: 64-col slice of 512
  const int n0 = blockIdx.y * 64;

  const float* W    = (cy < 2) ? Wq : (cy < 4) ? Wk : (cy < 6) ? Wv : Wskip;
  const float* bias = (cy < 2) ? bq : (cy < 4) ? bk : (cy < 6) ? bv : bskip;
  _Float16* dst     = (cy < 2) ? Q16 : (cy < 4) ? K16 : (cy < 6) ? V16 : S16;
  const int cb = (cy & 1) * 64;

  const int ty = tid >> 4, tx = tid & 15;
  const int lrow = tid >> 2, lk4 = (tid & 3) << 2;
  const int lc = tid & 63, lk0 = tid >> 6;

  float acc[4][4];
#pragma unroll
  for (int r = 0; r < 4; ++r)
#pragma unroll
    for (int j = 0; j < 4; ++j) acc[r][j] = 0.f;

  for (int kt = 0; kt < 128; kt += PBK) {
    float4 av = make_float4(0.f, 0.f, 0.f, 0.f);
    if (n0 + lrow < NN)
      av = *(const float4*)&x[(size_t)(n0 + lrow) * 128 + kt + lk4];
    a_s[lk4 + 0][lrow] = av.x; a_s[lk4 + 1][lrow] = av.y;
    a_s[lk4 + 2][lrow] = av.z; a_s[lk4 + 3][lrow] = av.w;
#pragma unroll
    for (int i = 0; i < 4; ++i) {
      int k = lk0 + (i << 2);
      b_s[k][lc] = W[(kt + k) * 128 + cb + lc];
    }
    __syncthreads();
#pragma unroll
    for (int k = 0; k < PBK; ++k) {
      float4 a = *(const float4*)&a_s[k][ty << 2];
      float4 b = *(const float4*)&b_s[k][tx << 2];
      acc[0][0] = fmaf(a.x, b.x, acc[0][0]); acc[0][1] = fmaf(a.x, b.y, acc[0][1]);
      acc[0][2] = fmaf(a.x, b.z, acc[0][2]); acc[0][3] = fmaf(a.x, b.w, acc[0][3]);
      acc[1][0] = fmaf(a.y, b.x, acc[1][0]); acc[1][1] = fmaf(a.y, b.y, acc[1][1]);
      acc[1][2] = fmaf(a.y, b.z, acc[1][2]); acc[1][3] = fmaf(a.y, b.w, acc[1][3]);
      acc[2][0] = fmaf(a.z, b.x, acc[2][0]); acc[2][1] = fmaf(a.z, b.y, acc[2][1]);
      acc[2][2] = fmaf(a.z, b.z, acc[2][2]); acc[2][3] = fmaf(a.z, b.w, acc[2][3]);
      acc[3][0] = fmaf(a.w, b.x, acc[3][0]); acc[3][1] = fmaf(a.w, b.y, acc[3][1]);
      acc[3][2] = fmaf(a.w, b.z, acc[3][2]); acc[3][3] = fmaf(a.w, b.w, acc[3][3]);
    }
    __syncthreads();
  }

  float4 bb = *(const float4*)&bias[cb + (tx << 2)];
#pragma unroll
  for (int r = 0; r < 4; ++r) {
#pragma unroll
    for (int j = 0; j < 4; ++j) acc[r][j] += (&bb.x)[j];
    int row = n0 + (ty << 2) + r;
    if (row < NN) {
      half4v h;
      h.x = (_Float16)acc[r][0]; h.y = (_Float16)acc[r][1];
      h.z = (_Float16)acc[r][2]; h.w = (_Float16)acc[r][3];
      *(half4v*)&dst[(size_t)row * 128 + cb + (tx << 2)] = h;
    }
  }

  if (cy >= 2) return;

  // ---- fused Z for heads {2cy, 2cy+1} ----
#pragma unroll
  for (int r = 0; r < 4; ++r) {
    qs2[(ty << 2) + r][2 * tx]     = pk16(acc[r][0], acc[r][1]);
    qs2[(ty << 2) + r][2 * tx + 1] = pk16(acc[r][2], acc[r][3]);
  }

  const int tn = tid >> 4, tj = tid & 15;
#pragma unroll
  for (int h2 = 0; h2 < 2; ++h2) {
    float acc2[4][7];
#pragma unroll
    for (int r = 0; r < 4; ++r)
#pragma unroll
      for (int c = 0; c < 7; ++c) acc2[r][c] = 0.f;

    for (int kc = 0; kc < 2; ++kc) {
      __syncthreads();
      for (int idx = tid; idx < 832; idx += 256) {
        int kp = idx & 7, j = idx >> 3;
        unsigned val = 0u;
        if (j < 101) {
          float2 wv = *(const float2*)&We[j * 128 + cy * 64 + h2 * 32 + kc * 16 + kp * 2];
          val = pk16(wv.x, wv.y);
        }
        wes2[kp][j] = val;
      }
      __syncthreads();
#pragma unroll
      for (int kp = 0; kp < 8; ++kp) {
#pragma unroll
        for (int r = 0; r < 4; ++r) {
          unsigned q2 = qs2[tn * 4 + r][h2 * 16 + kc * 8 + kp];
#pragma unroll
          for (int c = 0; c < 7; ++c) {
            int j = tj + 16 * c;
            if (j < 104) acc2[r][c] = fdot2f(q2, wes2[kp][j], acc2[r][c]);
          }
        }
      }
    }
#pragma unroll
    for (int r = 0; r < 4; ++r) {
      int row = n0 + tn * 4 + r;
      if (row < NN) {
#pragma unroll
        for (int c = 0; c < 7; ++c) {
          int j = tj + 16 * c;
          if (j < 104)
            Z16[(size_t)row * 416 + (cy * 2 + h2) * 104 + j] =
                (j <= 100) ? (_Float16)acc2[r][c] : (_Float16)0.f;
        }
      }
    }
  }
}

// ---------------- We^T A-fragment precompute (32 KB) -----------------------
__global__ void k_wefrag(const float* __restrict__ We, uint4* __restrict__ frag) {
  int idx = blockIdx.x * 256 + threadIdx.x;
  if (idx >= 2048) return;
  int lane = idx & 63, fi = idx >> 6;
  int ks = fi >> 3, mt = fi & 7;
  int ch = mt * 16 + (lane & 15);
  int k0 = ks * 32 + ((lane >> 4) << 3);
  U16 cv;
#pragma unroll
  for (int jj = 0; jj < 8; ++jj) {
    int j = k0 + jj;
    cv.h[jj] = (j <= 100) ? (_Float16)We[j * 128 + ch] : (_Float16)0.f;
  }
  frag[idx] = cv.u;
}

// ---------------- CSR build ----------------
__global__ void k_deg(const int* __restrict__ ei, int* __restrict__ deg) {
  int e = blockIdx.x * 256 + threadIdx.x;
  if (e < NE) atomicAdd(&deg[ei[NE + e]], 1);
}

#define SCHUNK 49
__global__ __launch_bounds__(1024) void k_scan(const int* __restrict__ deg,
                                               int* __restrict__ off) {
  __shared__ int s[1024];
  const int t = threadIdx.x;
  const int base = t * SCHUNK;
  int sum = 0;
#pragma unroll 7
  for (int i = 0; i < SCHUNK; ++i) {
    int idx = base + i;
    sum += (idx < NN) ? deg[idx] : 0;
  }
  s[t] = sum;
  __syncthreads();
  for (int o = 1; o < 1024; o <<= 1) {
    int v = 0;
    if (t >= o) v = s[t - o];
    __syncthreads();
    if (t >= o) s[t] += v;
    __syncthreads();
  }
  int run = s[t] - sum;
  for (int i = 0; i < SCHUNK; ++i) {
    int idx = base + i;
    if (idx < NN) { off[idx] = run; run += deg[idx]; }
  }
  if (t == 1023) off[NN] = s[1023];
}

__global__ void k_fill(const int* __restrict__ ei, const int* __restrict__ off,
                       int* __restrict__ cur, int* __restrict__ elist) {
  int e = blockIdx.x * 256 + threadIdx.x;
  if (e < NE) {
    int d = ei[NE + e];
    int p = atomicAdd(&cur[d], 1);
    elist[off[d] + p] = e;
  }
}

// ---------------- fused attention: one wave per dst node --------------------
// alpha via z-trick (no e before softmax); e via MFMA post-softmax, consumed
// per-mt (4-reg liveness). Lane (g = lane>>4, ed = lane&15).
__global__ __launch_bounds__(256, 4) void k_main(
    const _Float16* __restrict__ Q16, const _Float16* __restrict__ K16,
    const _Float16* __restrict__ V16, const _Float16* __restrict__ S16,
    const float* __restrict__ Wt, const float* __restrict__ bt,
    const uint4* __restrict__ wefrag, const unsigned* __restrict__ Z16u,
    const float* __restrict__ gamma, const float* __restrict__ beta,
    const float* __restrict__ msg, const int* __restrict__ last_update,
    const int* __restrict__ ei, const int* __restrict__ tt,
    const int* __restrict__ off, const int* __restrict__ elist,
    float* __restrict__ out)
{
  __shared__ uint4 wef_s[2048];        // 32 KB We^T A-fragments
  __shared__ float2 wtbt_s[104];
  __shared__ unsigned z_s[4][4][64];   // per-wave z f16-pairs [h][jp], padded
  __shared__ float accs_s[4][128];

  for (int i = threadIdx.x; i < 2048; i += 256) wef_s[i] = wefrag[i];
  if (threadIdx.x < 104) {
    int j = threadIdx.x;
    wtbt_s[j] = make_float2(j < TDIM ? Wt[j] : 0.f, j < TDIM ? bt[j] : 0.f);
  }

  const int wid = threadIdx.x >> 6, lane = threadIdx.x & 63;
  const int node = blockIdx.x * 4 + wid;          // grid = NN/4 exact
  const int g = lane >> 4, ed = lane & 15;

  {
    const unsigned* zrow = Z16u + (size_t)node * 208;
#pragma unroll
    for (int it = 0; it < 4; ++it) {
      int i = lane + it * 64;
      int h = i >> 6, jp = i & 63;
      ((unsigned*)z_s[wid])[i] = (jp < 52) ? zrow[h * 52 + jp] : 0u;
    }
  }
  __syncthreads();

  const int o0 = off[node];
  const int deg = off[node + 1] - o0;

  uint4 qa[4];
  {
    const uint4* qp = (const uint4*)&Q16[(size_t)node * 128 + g * 32];
#pragma unroll
    for (int i = 0; i < 4; ++i) qa[i] = qp[i];
  }

  float mh[4] = {-INFINITY, -INFINITY, -INFINITY, -INFINITY};
  float lh[4] = {0.f, 0.f, 0.f, 0.f};
  float acc[8][4] = {};

  for (int cbs = 0; cbs < deg; cbs += 16) {
    int cnt = deg - cbs; if (cnt > 16) cnt = 16;

    float rel = 0.f, mg = 0.f; int srcl = 0;
    if (lane < cnt) {
      int eid = elist[o0 + cbs + lane];
      srcl = ei[eid];
      mg = msg[eid];
      rel = (float)(last_update[srcl] - tt[eid]);
    }
    float rel_b = __shfl(rel, ed);
    float mg_b  = __shfl(mg, ed);
    int   src_b = __shfl(srcl, ed);
    const bool valid = (ed < cnt);

    // K row prefetch (64B, head g channels)
    uint4 ka[4];
    {
      const uint4* kp4 = (const uint4*)&K16[(size_t)src_b * 128 + g * 32];
#pragma unroll
      for (int i = 0; i < 4; ++i) ka[i] = kp4[i];
    }

    // attr -> f16 B-fragments + z-dot (alpha e-term)
    unsigned bfu[4][4];
    float zd[4] = {0.f, 0.f, 0.f, 0.f};
#pragma unroll
    for (int ks = 0; ks < 4; ++ks) {
#pragma unroll
      for (int p = 0; p < 4; ++p) {
        int j0 = ks * 32 + g * 8 + 2 * p;
        float a0 = 0.f, a1 = 0.f;
        if (valid) {
          if (ks < 3) {   // j0,j0+1 <= 95: always cos
            float2 w0 = wtbt_s[j0], w1 = wtbt_s[j0 + 1];
            a0 = ref_cosf(__fmaf_rn(rel_b, w0.x, w0.y));
            a1 = ref_cosf(__fmaf_rn(rel_b, w1.x, w1.y));
          } else {
            if (j0 < 100) {
              float2 w0 = wtbt_s[j0];
              a0 = ref_cosf(__fmaf_rn(rel_b, w0.x, w0.y));
            } else if (j0 == 100) a0 = mg_b;
            if (j0 + 1 < 100) {
              float2 w1 = wtbt_s[j0 + 1];
              a1 = ref_cosf(__fmaf_rn(rel_b, w1.x, w1.y));
            } else if (j0 + 1 == 100) a1 = mg_b;
          }
        }
        bfu[ks][p] = pk16(a0, a1);
      }
#pragma unroll
      for (int h = 0; h < 4; ++h) {
        uint2 za = *(const uint2*)&z_s[wid][h][ks * 16 + g * 4];
        uint2 zb = *(const uint2*)&z_s[wid][h][ks * 16 + g * 4 + 2];
        zd[h] = fdot2f(bfu[ks][0], za.x, zd[h]);
        zd[h] = fdot2f(bfu[ks][1], za.y, zd[h]);
        zd[h] = fdot2f(bfu[ks][2], zb.x, zd[h]);
        zd[h] = fdot2f(bfu[ks][3], zb.y, zd[h]);
      }
    }

    // q.k (head g fully within this lane)
    float qk = 0.f;
#pragma unroll
    for (int i = 0; i < 4; ++i) {
      qk = fdot2f(qa[i].x, ka[i].x, qk);
      qk = fdot2f(qa[i].y, ka[i].y, qk);
      qk = fdot2f(qa[i].z, ka[i].z, qk);
      qk = fdot2f(qa[i].w, ka[i].w, qk);
    }

    // alpha per head
    float al[4];
#pragma unroll
    for (int h = 0; h < 4; ++h) {
      float p = zd[h] + ((h == g) ? qk : 0.f);
      p += __shfl_xor(p, 16); p += __shfl_xor(p, 32);
      al[h] = valid ? p * 0.17677669529663689f : -INFINITY;
    }

    // online softmax per head (reduce over ed lanes)
    float w_[4], sc_[4];
#pragma unroll
    for (int h = 0; h < 4; ++h) {
      float bm = al[h];
      bm = fmaxf(bm, __shfl_xor(bm, 1)); bm = fmaxf(bm, __shfl_xor(bm, 2));
      bm = fmaxf(bm, __shfl_xor(bm, 4)); bm = fmaxf(bm, __shfl_xor(bm, 8));
      float nm = fmaxf(mh[h], bm);
      sc_[h] = __expf(mh[h] - nm);
      w_[h] = __expf(al[h] - nm);
      float ls = w_[h];
      ls += __shfl_xor(ls, 1); ls += __shfl_xor(ls, 2);
      ls += __shfl_xor(ls, 4); ls += __shfl_xor(ls, 8);
      lh[h] = lh[h] * sc_[h] + ls;
      mh[h] = nm;
    }

    // V phase: e per mt-tile via MFMA, consumed immediately
#pragma unroll
    for (int mt = 0; mt < 8; ++mt) {
      uint2 vv = *(const uint2*)&V16[(size_t)src_b * 128 + mt * 16 + g * 4];
      f32x4 c4 = {0.f, 0.f, 0.f, 0.f};
#pragma unroll
      for (int ks = 0; ks < 4; ++ks) {
        U16 av2; av2.u = wef_s[(ks * 8 + mt) * 64 + lane];
        U16 bv2; bv2.u.x = bfu[ks][0]; bv2.u.y = bfu[ks][1];
        bv2.u.z = bfu[ks][2]; bv2.u.w = bfu[ks][3];
        c4 = __builtin_amdgcn_mfma_f32_16x16x32_f16(av2.h, bv2.h, c4, 0, 0, 0);
      }
      U4h v0, v1; v0.u = vv.x; v1.u = vv.y;
      int hh = mt >> 1;
      acc[mt][0] = fmaf(w_[hh], (float)v0.h.x + c4[0], acc[mt][0] * sc_[hh]);
      acc[mt][1] = fmaf(w_[hh], (float)v0.h.y + c4[1], acc[mt][1] * sc_[hh]);
      acc[mt][2] = fmaf(w_[hh], (float)v1.h.x + c4[2], acc[mt][2] * sc_[hh]);
      acc[mt][3] = fmaf(w_[hh], (float)v1.h.y + c4[3], acc[mt][3] * sc_[hh]);
    }
  }

  // reduce acc over ed lanes; stash in LDS for channel-major epilogue
#pragma unroll
  for (int mt = 0; mt < 8; ++mt)
#pragma unroll
    for (int r = 0; r < 4; ++r) {
      float v = acc[mt][r];
      v += __shfl_xor(v, 1); v += __shfl_xor(v, 2);
      v += __shfl_xor(v, 4); v += __shfl_xor(v, 8);
      acc[mt][r] = v;
    }
  if (ed == 0) {
#pragma unroll
    for (int mt = 0; mt < 8; ++mt)
#pragma unroll
      for (int r = 0; r < 4; ++r)
        accs_s[wid][mt * 16 + g * 4 + r] = acc[mt][r];
  }
  __asm__ volatile("s_waitcnt lgkmcnt(0)" ::: "memory");

  // epilogue: skip + relu + layernorm; lane owns channels 2L, 2L+1
  float iv = 1.f / (lh[g] + 1e-16f);
  float2 av2 = *(const float2*)&accs_s[wid][2 * lane];
  U4h s2; s2.u = *(const unsigned*)&S16[(size_t)node * 128 + 2 * lane];
  float r0 = fmaxf(fmaf(av2.x, iv, (float)s2.h.x), 0.f);
  float r1 = fmaxf(fmaf(av2.y, iv, (float)s2.h.y), 0.f);

  float sum = r0 + r1;
#pragma unroll
  for (int o = 1; o < 64; o <<= 1) sum += __shfl_xor(sum, o);
  float mu = sum * 0.0078125f;
  float d0 = r0 - mu, d1 = r1 - mu;
  float vs = d0 * d0 + d1 * d1;
#pragma unroll
  for (int o = 1; o < 64; o <<= 1) vs += __shfl_xor(vs, o);
  float rstd = rsqrtf(vs * 0.0078125f + 1e-5f);
  float2 gm = ((const float2*)gamma)[lane], bb = ((const float2*)beta)[lane];
  ((float2*)out)[node * 64 + lane] =
      make_float2(d0 * rstd * gm.x + bb.x, d1 * rstd * gm.y + bb.y);
}

// ---------------- launch ----------------
// ws (bytes): Q16 0 | S16 12.8M | K16 25.6M | V16 38.4M | Z16 51.2M (41.6M)
//   deg 92.8M | cur 93.0M | off 93.2M | elist 93,400,064 | wef 96,600,064
//   end 96,632,832  (< proven 106,200,064)
extern "C" void kernel_launch(void* const* d_in, const int* in_sizes, int n_in,
                              void* d_out, int out_size, void* d_ws, size_t ws_size,
                              hipStream_t stream)
{
  (void)in_sizes; (void)n_in; (void)out_size;
  if (ws_size < 96632832u) return;

  const float* x     = (const float*)d_in[0];
  const float* msg   = (const float*)d_in[1];
  const float* Wt    = (const float*)d_in[2];
  const float* bt    = (const float*)d_in[3];
  const float* Wq    = (const float*)d_in[4];
  const float* bq    = (const float*)d_in[5];
  const float* Wk    = (const float*)d_in[6];
  const float* bk    = (const float*)d_in[7];
  const float* Wv    = (const float*)d_in[8];
  const float* bv    = (const float*)d_in[9];
  const float* We    = (const float*)d_in[10];
  const float* Wskip = (const float*)d_in[11];
  const float* bskip = (const float*)d_in[12];
  const float* gamma = (const float*)d_in[13];
  const float* beta  = (const float*)d_in[14];
  const int* last_update = (const int*)d_in[15];
  const int* ei    = (const int*)d_in[16];
  const int* tt    = (const int*)d_in[17];

  char* ws = (char*)d_ws;
  _Float16* Q16 = (_Float16*)(ws);
  _Float16* S16 = (_Float16*)(ws + 12800000);
  _Float16* K16 = (_Float16*)(ws + 25600000);
  _Float16* V16 = (_Float16*)(ws + 38400000);
  _Float16* Z16 = (_Float16*)(ws + 51200000);
  int* deg   = (int*)(ws + 92800000);
  int* cur   = (int*)(ws + 93000000);
  int* off   = (int*)(ws + 93200000);
  int* elist = (int*)(ws + 93400064);
  uint4* wef = (uint4*)(ws + 96600064);

  (void)hipMemsetAsync(deg, 0, 400000, stream);        // deg + cur
  k_wefrag<<<8, 256, 0, stream>>>(We, wef);
  k_deg <<<(NE + 255) / 256, 256, 0, stream>>>(ei, deg);
  k_scan<<<1, 1024, 0, stream>>>(deg, off);
  k_fill<<<(NE + 255) / 256, 256, 0, stream>>>(ei, off, cur, elist);
  dim3 pg(8, (NN + 63) / 64);
  k_proj<<<pg, 256, 0, stream>>>(x, Wq, bq, Wk, bk, Wv, bv, Wskip, bskip, We,
                                 Q16, K16, V16, S16, Z16);
  k_main<<<NN / 4, 256, 0, stream>>>(Q16, K16, V16, S16, Wt, bt, wef,
                                     (const unsigned*)Z16, gamma, beta,
                                     msg, last_update, ei, tt, off, elist,
                                     (float*)d_out);
}

// Round 6
// 963.120 us; speedup vs baseline: 1.7526x; 1.7526x over previous
//
#include <hip/hip_runtime.h>
#include <math.h>

#define NN 50000
#define NE 800000
#define TDIM 100

typedef _Float16 half2v __attribute__((ext_vector_type(2)));
typedef _Float16 half4v __attribute__((ext_vector_type(4)));
typedef _Float16 half8v __attribute__((ext_vector_type(8)));
typedef __fp16 fp16x2 __attribute__((ext_vector_type(2)));
typedef float f32x4 __attribute__((ext_vector_type(4)));

union U16 { uint4 u; half8v h; };
union U4h { unsigned u; half2v h; };

// cos(x) matching np.cos(float32) to ~1e-6: Cody-Waite into revolutions +
// hardware v_cos_f32.
__device__ __forceinline__ float ref_cosf(float x) {
  const float C1 = 0.15915494f;
  const float C2 = 6.42063831e-9f;
  float p = x * C1;
  float r = __fmaf_rn(x, C1, -p);
  r = __fmaf_rn(x, C2, r);
  float n = rintf(p);
  float f = (p - n) + r;
  return __builtin_amdgcn_cosf(f);
}

__device__ __forceinline__ float fdot2f(unsigned a, unsigned b, float c) {
  U4h ua, ub; ua.u = a; ub.u = b;
#if __has_builtin(__builtin_amdgcn_fdot2)
  return __builtin_amdgcn_fdot2(ua.h, ub.h, c, false);
#else
  return c + (float)ua.h.x * (float)ub.h.x + (float)ua.h.y * (float)ub.h.y;
#endif
}

__device__ __forceinline__ unsigned pk16(float a, float b) {
  fp16x2 h = __builtin_amdgcn_cvt_pkrtz(a, b);
  unsigned u;
  __builtin_memcpy(&u, &h, 4);
  return u;
}

// ---------------- projection GEMM + fused Z ----------------
// [NN,128] x [128,512] -> Q16|K16|V16|S16 (all f16).
// cy in {0,1} blocks additionally compute Z[n][h][j] = q_h . We_h[j]
// for their two heads (cy=0: h0,1; cy=1: h2,3) -> Z16 [n][4][104] f16.
#define PBK 16
__global__ void k_proj(
    const float* __restrict__ x,
    const float* __restrict__ Wq, const float* __restrict__ bq,
    const float* __restrict__ Wk, const float* __restrict__ bk,
    const float* __restrict__ Wv, const float* __restrict__ bv,
    const float* __restrict__ Wskip, const float* __restrict__ bskip,
    const float* __restrict__ We,
    _Float16* __restrict__ Q16, _Float16* __restrict__ K16,
    _Float16* __restrict__ V16, _Float16* __restrict__ S16,
    _Float16* __restrict__ Z16)
{
  __shared__ float a_s[PBK][68];
  __shared__ float b_s[PBK][64];
  __shared__ unsigned qs2[64][32];     // q as f16x2 pairs [row][k-pair]
  __shared__ unsigned wes2[8][104];    // We slice f16x2 [k-pair][j]

  const int tid = threadIdx.x;
  const int cy = blockIdx.x;              // 0..7: 64-col slice of 512
  const int n0 = blockIdx.y * 64;

  const float* W    = (cy < 2) ? Wq : (cy < 4) ? Wk : (cy < 6) ? Wv : Wskip;
  const float* bias = (cy < 2) ? bq : (cy < 4) ? bk : (cy < 6) ? bv : bskip;
  _Float16* dst     = (cy < 2) ? Q16 : (cy < 4) ? K16 : (cy < 6) ? V16 : S16;
  const int cb = (cy & 1) * 64;

  const int ty = tid >> 4, tx = tid & 15;
  const int lrow = tid >> 2, lk4 = (tid & 3) << 2;
  const int lc = tid & 63, lk0 = tid >> 6;

  float acc[4][4];
#pragma unroll
  for (int r = 0; r < 4; ++r)
#pragma unroll
    for (int j = 0; j < 4; ++j) acc[r][j] = 0.f;

  for (int kt = 0; kt < 128; kt += PBK) {
    float4 av = make_float4(0.f, 0.f, 0.f, 0.f);
    if (n0 + lrow < NN)
      av = *(const float4*)&x[(size_t)(n0 + lrow) * 128 + kt + lk4];
    a_s[lk4 + 0][lrow] = av.x; a_s[lk4 + 1][lrow] = av.y;
    a_s[lk4 + 2][lrow] = av.z; a_s[lk4 + 3][lrow] = av.w;
#pragma unroll
    for (int i = 0; i < 4; ++i) {
      int k = lk0 + (i << 2);
      b_s[k][lc] = W[(kt + k) * 128 + cb + lc];
    }
    __syncthreads();
#pragma unroll
    for (int k = 0; k < PBK; ++k) {
      float4 a = *(const float4*)&a_s[k][ty << 2];
      float4 b = *(const float4*)&b_s[k][tx << 2];
      acc[0][0] = fmaf(a.x, b.x, acc[0][0]); acc[0][1] = fmaf(a.x, b.y, acc[0][1]);
      acc[0][2] = fmaf(a.x, b.z, acc[0][2]); acc[0][3] = fmaf(a.x, b.w, acc[0][3]);
      acc[1][0] = fmaf(a.y, b.x, acc[1][0]); acc[1][1] = fmaf(a.y, b.y, acc[1][1]);
      acc[1][2] = fmaf(a.y, b.z, acc[1][2]); acc[1][3] = fmaf(a.y, b.w, acc[1][3]);
      acc[2][0] = fmaf(a.z, b.x, acc[2][0]); acc[2][1] = fmaf(a.z, b.y, acc[2][1]);
      acc[2][2] = fmaf(a.z, b.z, acc[2][2]); acc[2][3] = fmaf(a.z, b.w, acc[2][3]);
      acc[3][0] = fmaf(a.w, b.x, acc[3][0]); acc[3][1] = fmaf(a.w, b.y, acc[3][1]);
      acc[3][2] = fmaf(a.w, b.z, acc[3][2]); acc[3][3] = fmaf(a.w, b.w, acc[3][3]);
    }
    __syncthreads();
  }

  float4 bb = *(const float4*)&bias[cb + (tx << 2)];
#pragma unroll
  for (int r = 0; r < 4; ++r) {
#pragma unroll
    for (int j = 0; j < 4; ++j) acc[r][j] += (&bb.x)[j];
    int row = n0 + (ty << 2) + r;
    if (row < NN) {
      half4v h;
      h.x = (_Float16)acc[r][0]; h.y = (_Float16)acc[r][1];
      h.z = (_Float16)acc[r][2]; h.w = (_Float16)acc[r][3];
      *(half4v*)&dst[(size_t)row * 128 + cb + (tx << 2)] = h;
    }
  }

  if (cy >= 2) return;

  // ---- fused Z for heads {2cy, 2cy+1} ----
#pragma unroll
  for (int r = 0; r < 4; ++r) {
    qs2[(ty << 2) + r][2 * tx]     = pk16(acc[r][0], acc[r][1]);
    qs2[(ty << 2) + r][2 * tx + 1] = pk16(acc[r][2], acc[r][3]);
  }

  const int tn = tid >> 4, tj = tid & 15;
#pragma unroll
  for (int h2 = 0; h2 < 2; ++h2) {
    float acc2[4][7];
#pragma unroll
    for (int r = 0; r < 4; ++r)
#pragma unroll
      for (int c = 0; c < 7; ++c) acc2[r][c] = 0.f;

    for (int kc = 0; kc < 2; ++kc) {
      __syncthreads();
      for (int idx = tid; idx < 832; idx += 256) {
        int kp = idx & 7, j = idx >> 3;
        unsigned val = 0u;
        if (j < 101) {
          float2 wv = *(const float2*)&We[j * 128 + cy * 64 + h2 * 32 + kc * 16 + kp * 2];
          val = pk16(wv.x, wv.y);
        }
        wes2[kp][j] = val;
      }
      __syncthreads();
#pragma unroll
      for (int kp = 0; kp < 8; ++kp) {
#pragma unroll
        for (int r = 0; r < 4; ++r) {
          unsigned q2 = qs2[tn * 4 + r][h2 * 16 + kc * 8 + kp];
#pragma unroll
          for (int c = 0; c < 7; ++c) {
            int j = tj + 16 * c;
            if (j < 104) acc2[r][c] = fdot2f(q2, wes2[kp][j], acc2[r][c]);
          }
        }
      }
    }
#pragma unroll
    for (int r = 0; r < 4; ++r) {
      int row = n0 + tn * 4 + r;
      if (row < NN) {
#pragma unroll
        for (int c = 0; c < 7; ++c) {
          int j = tj + 16 * c;
          if (j < 104)
            Z16[(size_t)row * 416 + (cy * 2 + h2) * 104 + j] =
                (j <= 100) ? (_Float16)acc2[r][c] : (_Float16)0.f;
        }
      }
    }
  }
}

// ---------------- We^T A-fragment precompute (32 KB) -----------------------
__global__ void k_wefrag(const float* __restrict__ We, uint4* __restrict__ frag) {
  int idx = blockIdx.x * 256 + threadIdx.x;
  if (idx >= 2048) return;
  int lane = idx & 63, fi = idx >> 6;
  int ks = fi >> 3, mt = fi & 7;
  int ch = mt * 16 + (lane & 15);
  int k0 = ks * 32 + ((lane >> 4) << 3);
  U16 cv;
#pragma unroll
  for (int jj = 0; jj < 8; ++jj) {
    int j = k0 + jj;
    cv.h[jj] = (j <= 100) ? (_Float16)We[j * 128 + ch] : (_Float16)0.f;
  }
  frag[idx] = cv.u;
}

// ---------------- CSR build ----------------
__global__ void k_deg(const int* __restrict__ ei, int* __restrict__ deg) {
  int e = blockIdx.x * 256 + threadIdx.x;
  if (e < NE) atomicAdd(&deg[ei[NE + e]], 1);
}

#define SCHUNK 49
__global__ __launch_bounds__(1024) void k_scan(const int* __restrict__ deg,
                                               int* __restrict__ off) {
  __shared__ int s[1024];
  const int t = threadIdx.x;
  const int base = t * SCHUNK;
  int sum = 0;
#pragma unroll 7
  for (int i = 0; i < SCHUNK; ++i) {
    int idx = base + i;
    sum += (idx < NN) ? deg[idx] : 0;
  }
  s[t] = sum;
  __syncthreads();
  for (int o = 1; o < 1024; o <<= 1) {
    int v = 0;
    if (t >= o) v = s[t - o];
    __syncthreads();
    if (t >= o) s[t] += v;
    __syncthreads();
  }
  int run = s[t] - sum;
  for (int i = 0; i < SCHUNK; ++i) {
    int idx = base + i;
    if (idx < NN) { off[idx] = run; run += deg[idx]; }
  }
  if (t == 1023) off[NN] = s[1023];
}

__global__ void k_fill(const int* __restrict__ ei, const int* __restrict__ off,
                       int* __restrict__ cur, int* __restrict__ elist) {
  int e = blockIdx.x * 256 + threadIdx.x;
  if (e < NE) {
    int d = ei[NE + e];
    int p = atomicAdd(&cur[d], 1);
    elist[off[d] + p] = e;
  }
}

// ---------------- fused attention: one wave per dst node --------------------
// alpha via z-trick (no e before softmax); e via MFMA post-softmax, consumed
// per-mt (4-reg liveness). Lane (g = lane>>4, ed = lane&15).
// NOTE: __launch_bounds__(256) with NO min-waves arg: unified VGPR/AGPR file
// on gfx950 means an occupancy bound forces spills (R3: (256,3)->84 VGPR,
// 2.1GB scratch; R5: (256,4)->64 VGPR, 4.9GB scratch). Let the allocator
// take ~200 regs; occupancy 2/SIMD no-spill beats 4/SIMD with-spill.
__global__ __launch_bounds__(256) void k_main(
    const _Float16* __restrict__ Q16, const _Float16* __restrict__ K16,
    const _Float16* __restrict__ V16, const _Float16* __restrict__ S16,
    const float* __restrict__ Wt, const float* __restrict__ bt,
    const uint4* __restrict__ wefrag, const unsigned* __restrict__ Z16u,
    const float* __restrict__ gamma, const float* __restrict__ beta,
    const float* __restrict__ msg, const int* __restrict__ last_update,
    const int* __restrict__ ei, const int* __restrict__ tt,
    const int* __restrict__ off, const int* __restrict__ elist,
    float* __restrict__ out)
{
  __shared__ uint4 wef_s[2048];        // 32 KB We^T A-fragments
  __shared__ float2 wtbt_s[104];
  __shared__ unsigned z_s[4][4][64];   // per-wave z f16-pairs [h][jp], padded
  __shared__ float accs_s[4][128];

  for (int i = threadIdx.x; i < 2048; i += 256) wef_s[i] = wefrag[i];
  if (threadIdx.x < 104) {
    int j = threadIdx.x;
    wtbt_s[j] = make_float2(j < TDIM ? Wt[j] : 0.f, j < TDIM ? bt[j] : 0.f);
  }

  const int wid = threadIdx.x >> 6, lane = threadIdx.x & 63;
  const int node = blockIdx.x * 4 + wid;          // grid = NN/4 exact
  const int g = lane >> 4, ed = lane & 15;

  {
    const unsigned* zrow = Z16u + (size_t)node * 208;
#pragma unroll
    for (int it = 0; it < 4; ++it) {
      int i = lane + it * 64;
      int h = i >> 6, jp = i & 63;
      ((unsigned*)z_s[wid])[i] = (jp < 52) ? zrow[h * 52 + jp] : 0u;
    }
  }
  __syncthreads();

  const int o0 = off[node];
  const int deg = off[node + 1] - o0;

  uint4 qa[4];
  {
    const uint4* qp = (const uint4*)&Q16[(size_t)node * 128 + g * 32];
#pragma unroll
    for (int i = 0; i < 4; ++i) qa[i] = qp[i];
  }

  float mh[4] = {-INFINITY, -INFINITY, -INFINITY, -INFINITY};
  float lh[4] = {0.f, 0.f, 0.f, 0.f};
  float acc[8][4] = {};

  for (int cbs = 0; cbs < deg; cbs += 16) {
    int cnt = deg - cbs; if (cnt > 16) cnt = 16;

    float rel = 0.f, mg = 0.f; int srcl = 0;
    if (lane < cnt) {
      int eid = elist[o0 + cbs + lane];
      srcl = ei[eid];
      mg = msg[eid];
      rel = (float)(last_update[srcl] - tt[eid]);
    }
    float rel_b = __shfl(rel, ed);
    float mg_b  = __shfl(mg, ed);
    int   src_b = __shfl(srcl, ed);
    const bool valid = (ed < cnt);

    // K row prefetch (64B, head g channels)
    uint4 ka[4];
    {
      const uint4* kp4 = (const uint4*)&K16[(size_t)src_b * 128 + g * 32];
#pragma unroll
      for (int i = 0; i < 4; ++i) ka[i] = kp4[i];
    }

    // attr -> f16 B-fragments + z-dot (alpha e-term)
    unsigned bfu[4][4];
    float zd[4] = {0.f, 0.f, 0.f, 0.f};
#pragma unroll
    for (int ks = 0; ks < 4; ++ks) {
#pragma unroll
      for (int p = 0; p < 4; ++p) {
        int j0 = ks * 32 + g * 8 + 2 * p;
        float a0 = 0.f, a1 = 0.f;
        if (valid) {
          if (ks < 3) {   // j0,j0+1 <= 95: always cos
            float2 w0 = wtbt_s[j0], w1 = wtbt_s[j0 + 1];
            a0 = ref_cosf(__fmaf_rn(rel_b, w0.x, w0.y));
            a1 = ref_cosf(__fmaf_rn(rel_b, w1.x, w1.y));
          } else {
            if (j0 < 100) {
              float2 w0 = wtbt_s[j0];
              a0 = ref_cosf(__fmaf_rn(rel_b, w0.x, w0.y));
            } else if (j0 == 100) a0 = mg_b;
            if (j0 + 1 < 100) {
              float2 w1 = wtbt_s[j0 + 1];
              a1 = ref_cosf(__fmaf_rn(rel_b, w1.x, w1.y));
            } else if (j0 + 1 == 100) a1 = mg_b;
          }
        }
        bfu[ks][p] = pk16(a0, a1);
      }
#pragma unroll
      for (int h = 0; h < 4; ++h) {
        uint2 za = *(const uint2*)&z_s[wid][h][ks * 16 + g * 4];
        uint2 zb = *(const uint2*)&z_s[wid][h][ks * 16 + g * 4 + 2];
        zd[h] = fdot2f(bfu[ks][0], za.x, zd[h]);
        zd[h] = fdot2f(bfu[ks][1], za.y, zd[h]);
        zd[h] = fdot2f(bfu[ks][2], zb.x, zd[h]);
        zd[h] = fdot2f(bfu[ks][3], zb.y, zd[h]);
      }
    }

    // q.k (head g fully within this lane)
    float qk = 0.f;
#pragma unroll
    for (int i = 0; i < 4; ++i) {
      qk = fdot2f(qa[i].x, ka[i].x, qk);
      qk = fdot2f(qa[i].y, ka[i].y, qk);
      qk = fdot2f(qa[i].z, ka[i].z, qk);
      qk = fdot2f(qa[i].w, ka[i].w, qk);
    }

    // alpha per head
    float al[4];
#pragma unroll
    for (int h = 0; h < 4; ++h) {
      float p = zd[h] + ((h == g) ? qk : 0.f);
      p += __shfl_xor(p, 16); p += __shfl_xor(p, 32);
      al[h] = valid ? p * 0.17677669529663689f : -INFINITY;
    }

    // online softmax per head (reduce over ed lanes)
    float w_[4], sc_[4];
#pragma unroll
    for (int h = 0; h < 4; ++h) {
      float bm = al[h];
      bm = fmaxf(bm, __shfl_xor(bm, 1)); bm = fmaxf(bm, __shfl_xor(bm, 2));
      bm = fmaxf(bm, __shfl_xor(bm, 4)); bm = fmaxf(bm, __shfl_xor(bm, 8));
      float nm = fmaxf(mh[h], bm);
      sc_[h] = __expf(mh[h] - nm);
      w_[h] = __expf(al[h] - nm);
      float ls = w_[h];
      ls += __shfl_xor(ls, 1); ls += __shfl_xor(ls, 2);
      ls += __shfl_xor(ls, 4); ls += __shfl_xor(ls, 8);
      lh[h] = lh[h] * sc_[h] + ls;
      mh[h] = nm;
    }

    // V phase: e per mt-tile via MFMA, consumed immediately
#pragma unroll
    for (int mt = 0; mt < 8; ++mt) {
      uint2 vv = *(const uint2*)&V16[(size_t)src_b * 128 + mt * 16 + g * 4];
      f32x4 c4 = {0.f, 0.f, 0.f, 0.f};
#pragma unroll
      for (int ks = 0; ks < 4; ++ks) {
        U16 av2; av2.u = wef_s[(ks * 8 + mt) * 64 + lane];
        U16 bv2; bv2.u.x = bfu[ks][0]; bv2.u.y = bfu[ks][1];
        bv2.u.z = bfu[ks][2]; bv2.u.w = bfu[ks][3];
        c4 = __builtin_amdgcn_mfma_f32_16x16x32_f16(av2.h, bv2.h, c4, 0, 0, 0);
      }
      U4h v0, v1; v0.u = vv.x; v1.u = vv.y;
      int hh = mt >> 1;
      acc[mt][0] = fmaf(w_[hh], (float)v0.h.x + c4[0], acc[mt][0] * sc_[hh]);
      acc[mt][1] = fmaf(w_[hh], (float)v0.h.y + c4[1], acc[mt][1] * sc_[hh]);
      acc[mt][2] = fmaf(w_[hh], (float)v1.h.x + c4[2], acc[mt][2] * sc_[hh]);
      acc[mt][3] = fmaf(w_[hh], (float)v1.h.y + c4[3], acc[mt][3] * sc_[hh]);
    }
  }

  // reduce acc over ed lanes; stash in LDS for channel-major epilogue
#pragma unroll
  for (int mt = 0; mt < 8; ++mt)
#pragma unroll
    for (int r = 0; r < 4; ++r) {
      float v = acc[mt][r];
      v += __shfl_xor(v, 1); v += __shfl_xor(v, 2);
      v += __shfl_xor(v, 4); v += __shfl_xor(v, 8);
      acc[mt][r] = v;
    }
  if (ed == 0) {
#pragma unroll
    for (int mt = 0; mt < 8; ++mt)
#pragma unroll
      for (int r = 0; r < 4; ++r)
        accs_s[wid][mt * 16 + g * 4 + r] = acc[mt][r];
  }
  __asm__ volatile("s_waitcnt lgkmcnt(0)" ::: "memory");

  // epilogue: skip + relu + layernorm; lane owns channels 2L, 2L+1
  float iv = 1.f / (lh[g] + 1e-16f);
  float2 av2 = *(const float2*)&accs_s[wid][2 * lane];
  U4h s2; s2.u = *(const unsigned*)&S16[(size_t)node * 128 + 2 * lane];
  float r0 = fmaxf(fmaf(av2.x, iv, (float)s2.h.x), 0.f);
  float r1 = fmaxf(fmaf(av2.y, iv, (float)s2.h.y), 0.f);

  float sum = r0 + r1;
#pragma unroll
  for (int o = 1; o < 64; o <<= 1) sum += __shfl_xor(sum, o);
  float mu = sum * 0.0078125f;
  float d0 = r0 - mu, d1 = r1 - mu;
  float vs = d0 * d0 + d1 * d1;
#pragma unroll
  for (int o = 1; o < 64; o <<= 1) vs += __shfl_xor(vs, o);
  float rstd = rsqrtf(vs * 0.0078125f + 1e-5f);
  float2 gm = ((const float2*)gamma)[lane], bb = ((const float2*)beta)[lane];
  ((float2*)out)[node * 64 + lane] =
      make_float2(d0 * rstd * gm.x + bb.x, d1 * rstd * gm.y + bb.y);
}

// ---------------- launch ----------------
// ws (bytes): Q16 0 | S16 12.8M | K16 25.6M | V16 38.4M | Z16 51.2M (41.6M)
//   deg 92.8M | cur 93.0M | off 93.2M | elist 93,400,064 | wef 96,600,064
//   end 96,632,832  (< proven 106,200,064)
extern "C" void kernel_launch(void* const* d_in, const int* in_sizes, int n_in,
                              void* d_out, int out_size, void* d_ws, size_t ws_size,
                              hipStream_t stream)
{
  (void)in_sizes; (void)n_in; (void)out_size;
  if (ws_size < 96632832u) return;

  const float* x     = (const float*)d_in[0];
  const float* msg   = (const float*)d_in[1];
  const float* Wt    = (const float*)d_in[2];
  const float* bt    = (const float*)d_in[3];
  const float* Wq    = (const float*)d_in[4];
  const float* bq    = (const float*)d_in[5];
  const float* Wk    = (const float*)d_in[6];
  const float* bk    = (const float*)d_in[7];
  const float* Wv    = (const float*)d_in[8];
  const float* bv    = (const float*)d_in[9];
  const float* We    = (const float*)d_in[10];
  const float* Wskip = (const float*)d_in[11];
  const float* bskip = (const float*)d_in[12];
  const float* gamma = (const float*)d_in[13];
  const float* beta  = (const float*)d_in[14];
  const int* last_update = (const int*)d_in[15];
  const int* ei    = (const int*)d_in[16];
  const int* tt    = (const int*)d_in[17];

  char* ws = (char*)d_ws;
  _Float16* Q16 = (_Float16*)(ws);
  _Float16* S16 = (_Float16*)(ws + 12800000);
  _Float16* K16 = (_Float16*)(ws + 25600000);
  _Float16* V16 = (_Float16*)(ws + 38400000);
  _Float16* Z16 = (_Float16*)(ws + 51200000);
  int* deg   = (int*)(ws + 92800000);
  int* cur   = (int*)(ws + 93000000);
  int* off   = (int*)(ws + 93200000);
  int* elist = (int*)(ws + 93400064);
  uint4* wef = (uint4*)(ws + 96600064);

  (void)hipMemsetAsync(deg, 0, 400000, stream);        // deg + cur
  k_wefrag<<<8, 256, 0, stream>>>(We, wef);
  k_deg <<<(NE + 255) / 256, 256, 0, stream>>>(ei, deg);
  k_scan<<<1, 1024, 0, stream>>>(deg, off);
  k_fill<<<(NE + 255) / 256, 256, 0, stream>>>(ei, off, cur, elist);
  dim3 pg(8, (NN + 63) / 64);
  k_proj<<<pg, 256, 0, stream>>>(x, Wq, bq, Wk, bk, Wv, bv, Wskip, bskip, We,
                                 Q16, K16, V16, S16, Z16);
  k_main<<<NN / 4, 256, 0, stream>>>(Q16, K16, V16, S16, Wt, bt, wef,
                                     (const unsigned*)Z16, gamma, beta,
                                     msg, last_update, ei, tt, off, elist,
                                     (float*)d_out);
}